// Round 8
// baseline (4017.756 us; speedup 1.0000x reference)
//
#include <hip/hip_runtime.h>
#include <math.h>
#include <float.h>
#include <limits.h>

#define B_ 8
#define C_ 32
#define N_ 4096
#define K_ 16
#define L_ 20   // per-lane fp32 candidate list (margin 4 over 16)

typedef __attribute__((ext_vector_type(8))) short bf16x8;
typedef __attribute__((ext_vector_type(4))) float f32x4;
#define MFMA16(a, b, c) __builtin_amdgcn_mfma_f32_16x16x32_bf16(a, b, c, 0, 0, 0)

// ------------------------------------------------------------------
// ws layout (bytes):
//   yT  : [B][N][96] float    12,582,912
//   sqd : [B][N]     double      262,144
//   sq  : [B][N]     float       131,072
//   knn : [B][N][16] int       2,097,152
//   hBs : swizzled bf16 hi     6,291,456   (frag-major: [g16][sl][lane][8])
//   lBs : swizzled bf16 lo     6,291,456
//   Ek/Ev/Eq floats               20,480
// ------------------------------------------------------------------

__global__ __launch_bounds__(256) void kE_combine(
    const float* __restrict__ Wk, const float* __restrict__ Dk,
    const float* __restrict__ Wv, const float* __restrict__ Dv,
    const float* __restrict__ Wq, const float* __restrict__ Dq,
    float* __restrict__ Ek, float* __restrict__ Ev, float* __restrict__ Eq) {
  int t = threadIdx.x;
  for (int e = t; e < 2048; e += 256) {
    int o = e >> 6, c = e & 63;
    float a = 0.f, v = 0.f;
    for (int m = 0; m < 32; ++m) {
      a = fmaf(Dk[o * 32 + m], Wk[m * 64 + c], a);
      v = fmaf(Dv[o * 32 + m], Wv[m * 64 + c], v);
    }
    Ek[e] = a; Ev[e] = v;
  }
  for (int e = t; e < 1024; e += 256) {
    int o = e >> 5, c = e & 31;
    float a = 0.f;
    for (int m = 0; m < 32; ++m) a = fmaf(Dq[o * 32 + m], Wq[m * 32 + c], a);
    Eq[e] = a;
  }
}

// transpose y -> yT; sq fp32; sqd fp64; hBs/lBs = bf16 hi/lo split stored
// FRAGMENT-MAJOR: addr = ((g16*3 + sl)*64 + lane)*8 + e, lane=(fg<<4)|fm,
// point n = g16*16+fm, k-dim d = sl*32 + fg*8 + e.
__global__ __launch_bounds__(256) void kA_transpose(
    const float* __restrict__ y, float* __restrict__ yT,
    float* __restrict__ sq, double* __restrict__ sqd,
    ushort* __restrict__ hBs, ushort* __restrict__ lBs) {
  __shared__ float tile[96][65];
  int b = blockIdx.x >> 6;
  int n0 = (blockIdx.x & 63) * 64;
  int t = threadIdx.x;
  int g = t >> 6, ln = t & 63;
  #pragma unroll
  for (int r = 0; r < 24; ++r) {
    int d = g * 24 + r;
    tile[d][ln] = y[((size_t)b * 96 + d) * N_ + n0 + ln];
  }
  __syncthreads();
  if (t < 64) {
    float s = 0.f; double sd = 0.0;
    #pragma unroll
    for (int d = 0; d < 96; ++d) {
      float v = tile[d][t];
      s = fmaf(v, v, s);
      sd += (double)v * (double)v;
    }
    sq[b * N_ + n0 + t] = s;
    sqd[b * N_ + n0 + t] = sd;
  }
  for (int idx = t; idx < 64 * 96; idx += 256) {
    int nl = idx / 96, d = idx % 96;
    yT[((size_t)b * N_ + n0 + nl) * 96 + d] = tile[d][nl];
  }
  for (int idx = t; idx < 768; idx += 256) {
    int g16l = idx / 192;
    int rem = idx - g16l * 192;
    int sl = rem >> 6;
    int ln2 = rem & 63;
    int fg2 = ln2 >> 4, fm2 = ln2 & 15;
    int nl = g16l * 16 + fm2;
    uint hw[4], lw[4];
    #pragma unroll
    for (int e2 = 0; e2 < 4; ++e2) {
      float v0 = tile[sl * 32 + fg2 * 8 + 2 * e2][nl];
      float v1 = tile[sl * 32 + fg2 * 8 + 2 * e2 + 1][nl];
      uint x0 = __float_as_uint(v0), x1 = __float_as_uint(v1);
      uint h0 = x0 >> 16, h1 = x1 >> 16;
      float r0 = v0 - __uint_as_float(h0 << 16);
      float r1 = v1 - __uint_as_float(h1 << 16);
      uint l0 = __float_as_uint(r0) >> 16, l1 = __float_as_uint(r1) >> 16;
      hw[e2] = h0 | (h1 << 16);
      lw[e2] = l0 | (l1 << 16);
    }
    size_t off = (size_t)b * 393216 +
                 (((size_t)(n0 >> 4) + g16l) * 3 + sl) * 512 + (size_t)ln2 * 8;
    *(uint4*)(hBs + off) = make_uint4(hw[0], hw[1], hw[2], hw[3]);
    *(uint4*)(lBs + off) = make_uint4(lw[0], lw[1], lw[2], lw[3]);
  }
}

// kNN: block = 16 queries x 4 j-chunk waves (2048 blocks, 8192 waves).
// Wave w scans j in [w*1024,(w+1)*1024): 16 tiles x {24 coalesced frag
// loads, 36 MFMA}; lane (fg,fm) keeps in-register top-20 of its 256
// scores for query q=qg*16+fm. Epilogue: 16-way exact merge of the
// per-lane sorted lists -> fp64 re-score of 20 -> exact sorted top-16.
__global__ __launch_bounds__(256) void kB_knn(
    const float* __restrict__ yT, const ushort* __restrict__ hBs,
    const ushort* __restrict__ lBs, const float* __restrict__ sq,
    const double* __restrict__ sqd, int* __restrict__ knn) {
  __shared__ float  lv[4][4][16][L_ + 1];   // [w][fg][fm][slot]
  __shared__ int    li[4][4][16][L_ + 1];
  __shared__ float  mv[16][L_];
  __shared__ int    mid[16][L_];
  __shared__ double rv[16][L_];

  const int t = threadIdx.x;
  const int lane = t & 63;
  const int w = t >> 6;
  const int fg = lane >> 4, fm = lane & 15;
  const int b = blockIdx.x & 7;             // XCD-friendly batch pinning
  const int qg = blockIdx.x >> 3;           // 0..255
  const int q = qg * 16 + fm;
  const size_t bN = (size_t)b * N_;
  const ushort* hb = hBs + bN * 96;
  const ushort* lb = lBs + bN * 96;
  const float* sqb = sq + bN;
  const float sqi = sqb[q];

  // resident query frags (B operand): h and l, 3 k-segments each
  const ushort* hqb = hb + (size_t)qg * 1536 + (size_t)lane * 8;
  const ushort* lqb = lb + (size_t)qg * 1536 + (size_t)lane * 8;
  const bf16x8 qh0 = *(const bf16x8*)(hqb);
  const bf16x8 qh1 = *(const bf16x8*)(hqb + 512);
  const bf16x8 qh2 = *(const bf16x8*)(hqb + 1024);
  const bf16x8 ql0 = *(const bf16x8*)(lqb);
  const bf16x8 ql1 = *(const bf16x8*)(lqb + 512);
  const bf16x8 ql2 = *(const bf16x8*)(lqb + 1024);

  float vals[L_]; int idxs[L_];
  #pragma unroll
  for (int i = 0; i < L_; ++i) { vals[i] = -FLT_MAX; idxs[i] = 0; }

  const int jchunk = w * 1024;
  #pragma unroll 1
  for (int jt = 0; jt < 16; ++jt) {
    const int g16 = (jchunk >> 4) + jt * 4;
    const ushort* hpb = hb + (size_t)g16 * 1536 + (size_t)lane * 8;
    const ushort* lpb = lb + (size_t)g16 * 1536 + (size_t)lane * 8;
    #pragma unroll
    for (int jb = 0; jb < 4; ++jb) {
      const ushort* ph = hpb + jb * 1536;
      const ushort* pl = lpb + jb * 1536;
      const bf16x8 a0 = *(const bf16x8*)(ph);
      const bf16x8 a1 = *(const bf16x8*)(ph + 512);
      const bf16x8 a2 = *(const bf16x8*)(ph + 1024);
      const bf16x8 b0 = *(const bf16x8*)(pl);
      const bf16x8 b1 = *(const bf16x8*)(pl + 512);
      const bf16x8 b2 = *(const bf16x8*)(pl + 1024);
      f32x4 c = {0.f, 0.f, 0.f, 0.f};
      c = MFMA16(a0, qh0, c);   // h_j . h_q
      c = MFMA16(a1, qh1, c);
      c = MFMA16(a2, qh2, c);
      c = MFMA16(a0, ql0, c);   // h_j . l_q
      c = MFMA16(a1, ql1, c);
      c = MFMA16(a2, ql2, c);
      c = MFMA16(b0, qh0, c);   // l_j . h_q
      c = MFMA16(b1, qh1, c);
      c = MFMA16(b2, qh2, c);
      const int jbase = jchunk + jt * 64 + jb * 16 + fg * 4;
      const float4 s4 = *(const float4*)(sqb + jbase);
      #pragma unroll
      for (int r = 0; r < 4; ++r) {
        const float sj = r == 0 ? s4.x : r == 1 ? s4.y : r == 2 ? s4.z : s4.w;
        const float neg = 2.f * c[r] - sqi - sj;
        if (neg > vals[L_ - 1]) {        // strict >: earlier index wins
          float v = neg; int id = jbase + r;
          #pragma unroll
          for (int i = 0; i < L_; ++i) {
            if (v > vals[i]) {
              float tv = vals[i]; vals[i] = v; v = tv;
              int ti = idxs[i]; idxs[i] = id; id = ti;
            }
          }
        }
      }
    }
  }

  // ---- per-lane sorted lists + sentinel ----
  #pragma unroll
  for (int r = 0; r < L_; ++r) { lv[w][fg][fm][r] = vals[r]; li[w][fg][fm][r] = idxs[r]; }
  lv[w][fg][fm][L_] = -FLT_MAX; li[w][fg][fm][L_] = INT_MAX;
  __syncthreads();

  // ---- 16-way exact merge (threads 0..15, one per query) ----
  if (t < 16) {
    int p[16];
    #pragma unroll
    for (int c2 = 0; c2 < 16; ++c2) p[c2] = 0;
    #pragma unroll 1
    for (int r = 0; r < L_; ++r) {
      float bv = -FLT_MAX; int bi2 = INT_MAX; int bc = 0;
      #pragma unroll
      for (int c2 = 0; c2 < 16; ++c2) {
        float v = lv[c2 >> 2][c2 & 3][t][p[c2]];
        int  id = li[c2 >> 2][c2 & 3][t][p[c2]];
        if (v > bv || (v == bv && id < bi2)) { bv = v; bi2 = id; bc = c2; }
      }
      mv[t][r] = bv; mid[t][r] = bi2;
      #pragma unroll
      for (int c2 = 0; c2 < 16; ++c2) p[c2] += (bc == c2);
    }
  }
  __syncthreads();

  // ---- fp64 exact re-score: 320 tasks (16 q x 20 cand) ----
  {
    const double* sqdb = sqd + bN;
    const float* yTb = yT + bN * 96;
    #pragma unroll 1
    for (int task = t; task < 16 * L_; task += 256) {
      const int fq = task / L_, slot = task - fq * L_;
      const int qq = qg * 16 + fq;
      const int j = mid[fq][slot];
      const float4* q4p = (const float4*)(yTb + (size_t)qq * 96);
      const float4* p4p = (const float4*)(yTb + (size_t)j * 96);
      double a0 = 0.0, a1 = 0.0, a2 = 0.0, a3 = 0.0;
      #pragma unroll 4
      for (int m = 0; m < 24; ++m) {
        float4 qm = q4p[m], pm = p4p[m];
        a0 += (double)qm.x * (double)pm.x;
        a1 += (double)qm.y * (double)pm.y;
        a2 += (double)qm.z * (double)pm.z;
        a3 += (double)qm.w * (double)pm.w;
      }
      rv[fq][slot] = 2.0 * ((a0 + a1) + (a2 + a3)) - sqdb[qq] - sqdb[j];
    }
  }
  __syncthreads();

  // ---- final exact sorted top-16 (threads 0..15) ----
  if (t < 16) {
    double bd[16]; int bix[16];
    #pragma unroll
    for (int i = 0; i < 16; ++i) { bd[i] = -DBL_MAX; bix[i] = INT_MAX; }
    #pragma unroll 1
    for (int r = 0; r < L_; ++r) {
      double v = rv[t][r]; int id = mid[t][r];
      if (v > bd[15] || (v == bd[15] && id < bix[15])) {
        #pragma unroll
        for (int i = 0; i < 16; ++i) {
          if (v > bd[i] || (v == bd[i] && id < bix[i])) {
            double tv = bd[i]; bd[i] = v; v = tv;
            int ti = bix[i]; bix[i] = id; id = ti;
          }
        }
      }
    }
    int* outp = knn + (bN + (size_t)(qg * 16 + t)) * 16;
    #pragma unroll
    for (int r = 0; r < 16; ++r) outp[r] = bix[r];
  }
}

__device__ __forceinline__ float f4e(const float4& v, int i) {
  return i == 0 ? v.x : i == 1 ? v.y : i == 2 ? v.z : v.w;
}

// Fused main (unchanged).
__global__ __launch_bounds__(256) void kC_main(
    const float* __restrict__ x, const float* __restrict__ yT,
    const int* __restrict__ knn,
    const float* __restrict__ Wq, const float* __restrict__ Eq,
    const float* __restrict__ Wk, const float* __restrict__ Ek,
    const float* __restrict__ Wv, const float* __restrict__ Ev,
    float* __restrict__ out) {
  __shared__ float4 sWq[8 * 32], sEq[8 * 32];
  __shared__ float4 sWk[16 * 32], sEk[16 * 32], sWv[16 * 32], sEv[16 * 32];
  __shared__ float sOut[8][97];

  int t = threadIdx.x;
  {
    int e = t;
    int c4 = e >> 5, o = e & 31;
    sWq[e] = ((const float4*)(Wq + o * 32))[c4];
    sEq[e] = ((const float4*)(Eq + o * 32))[c4];
  }
  for (int e = t; e < 512; e += 256) {
    int c4 = e >> 5, o = e & 31;
    sWk[e] = ((const float4*)(Wk + o * 64))[c4];
    sEk[e] = ((const float4*)(Ek + o * 64))[c4];
    sWv[e] = ((const float4*)(Wv + o * 64))[c4];
    sEv[e] = ((const float4*)(Ev + o * 64))[c4];
  }
  __syncthreads();

  int q = t >> 5, o = t & 31;
  int bno = blockIdx.x;
  int b = bno >> 9;
  int n = ((bno & 511) << 3) + q;
  int h = o >> 4, kk_mine = o & 15;

  const float* xb = x + (size_t)b * 96 * N_ + n;
  float pq[3] = {0, 0, 0}, dq[3] = {0, 0, 0};
  #pragma unroll
  for (int c4 = 0; c4 < 8; ++c4) {
    float4 wq = sWq[c4 * 32 + o], eq = sEq[c4 * 32 + o];
    #pragma unroll
    for (int i = 0; i < 4; ++i) {
      int c = c4 * 4 + i;
      float w = f4e(wq, i), e2 = f4e(eq, i);
      #pragma unroll
      for (int d = 0; d < 3; ++d) {
        float xv = xb[(size_t)(c * 3 + d) * N_];
        pq[d] = fmaf(w, xv, pq[d]);
        dq[d] = fmaf(e2, xv, dq[d]);
      }
    }
  }
  float Qx[3];
  {
    float dot = pq[0] * dq[0] + pq[1] * dq[1] + pq[2] * dq[2];
    float dsq = dq[0] * dq[0] + dq[1] * dq[1] + dq[2] * dq[2] + 1e-6f;
    float r = dot / dsq;
    float qv[3];
    #pragma unroll
    for (int d = 0; d < 3; ++d) {
      float pn = pq[d] - r * dq[d];
      qv[d] = 0.2f * pq[d] + 0.8f * (dot >= 0.f ? pq[d] : pn);
    }
    float nn = sqrtf(qv[0] * qv[0] + qv[1] * qv[1] + qv[2] * qv[2]);
    float nch2 = nn * nn;
    #pragma unroll
    for (int m = 1; m <= 16; m <<= 1) nch2 += __shfl_xor(nch2, m, 32);
    float s = (nn / fmaxf(sqrtf(nch2), 1e-12f)) / fmaxf(nn, 1e-12f);
    #pragma unroll
    for (int d = 0; d < 3; ++d) Qx[d] = qv[d] * s;
  }

  const float* ctr = yT + ((size_t)b * N_ + n) * 96;
  const int* kidx = knn + ((size_t)b * N_ + n) * 16;

  float pck[3] = {0, 0, 0}, dck[3] = {0, 0, 0};
  #pragma unroll
  for (int c4 = 0; c4 < 8; ++c4) {
    float4 wlo = sWk[c4 * 32 + o], whi = sWk[(c4 + 8) * 32 + o];
    float4 elo = sEk[c4 * 32 + o], ehi = sEk[(c4 + 8) * 32 + o];
    float4 c0 = ((const float4*)ctr)[c4 * 3 + 0];
    float4 c1 = ((const float4*)ctr)[c4 * 3 + 1];
    float4 c2 = ((const float4*)ctr)[c4 * 3 + 2];
    float cv[12] = {c0.x, c0.y, c0.z, c0.w, c1.x, c1.y, c1.z, c1.w, c2.x, c2.y, c2.z, c2.w};
    #pragma unroll
    for (int v = 0; v < 12; ++v) {
      int cl = v / 3, d = v % 3;
      pck[d] = fmaf(f4e(whi, cl) - f4e(wlo, cl), cv[v], pck[d]);
      dck[d] = fmaf(f4e(ehi, cl) - f4e(elo, cl), cv[v], dck[d]);
    }
  }

  float myscore = 0.f;
  #pragma unroll 1
  for (int k = 0; k < 16; ++k) {
    int jn = kidx[k];
    const float* nb = yT + ((size_t)b * N_ + jn) * 96;
    float p[3] = {pck[0], pck[1], pck[2]}, dd[3] = {dck[0], dck[1], dck[2]};
    #pragma unroll
    for (int c4 = 0; c4 < 8; ++c4) {
      float4 w = sWk[c4 * 32 + o], e = sEk[c4 * 32 + o];
      float4 n0 = ((const float4*)nb)[c4 * 3 + 0];
      float4 n1 = ((const float4*)nb)[c4 * 3 + 1];
      float4 n2 = ((const float4*)nb)[c4 * 3 + 2];
      float nv[12] = {n0.x, n0.y, n0.z, n0.w, n1.x, n1.y, n1.z, n1.w, n2.x, n2.y, n2.z, n2.w};
      #pragma unroll
      for (int v = 0; v < 12; ++v) {
        int cl = v / 3, d = v % 3;
        p[d]  = fmaf(f4e(w, cl), nv[v], p[d]);
        dd[d] = fmaf(f4e(e, cl), nv[v], dd[d]);
      }
    }
    float dot = p[0] * dd[0] + p[1] * dd[1] + p[2] * dd[2];
    float dsq = dd[0] * dd[0] + dd[1] * dd[1] + dd[2] * dd[2] + 1e-6f;
    float r = dot / dsq;
    float ky[3];
    #pragma unroll
    for (int d = 0; d < 3; ++d) {
      float pn = p[d] - r * dd[d];
      ky[d] = 0.2f * p[d] + 0.8f * (dot >= 0.f ? p[d] : pn);
    }
    float nn = sqrtf(ky[0] * ky[0] + ky[1] * ky[1] + ky[2] * ky[2]);
    float nch2 = nn * nn;
    #pragma unroll
    for (int m = 1; m <= 16; m <<= 1) nch2 += __shfl_xor(nch2, m, 32);
    float s = (1.f / fmaxf(sqrtf(nch2), 1e-12f)) * (nn / fmaxf(nn, 1e-12f));
    float qk = (ky[0] * Qx[0] + ky[1] * Qx[1] + ky[2] * Qx[2]) * s;
    #pragma unroll
    for (int m = 1; m <= 8; m <<= 1) qk += __shfl_xor(qk, m, 32);
    float score = qk * 0.14433756729740643f;   // 1/sqrt(48)
    if (kk_mine == k) myscore = score;
  }

  float att_mine;
  {
    float mx = myscore;
    #pragma unroll
    for (int m = 1; m <= 8; m <<= 1) mx = fmaxf(mx, __shfl_xor(mx, m, 32));
    float ex = expf(myscore - mx);
    float ss = ex;
    #pragma unroll
    for (int m = 1; m <= 8; m <<= 1) ss += __shfl_xor(ss, m, 32);
    att_mine = ex / ss;
  }

  float pcv[3] = {0, 0, 0}, dcv[3] = {0, 0, 0};
  #pragma unroll
  for (int c4 = 0; c4 < 8; ++c4) {
    float4 wlo = sWv[c4 * 32 + o], whi = sWv[(c4 + 8) * 32 + o];
    float4 elo = sEv[c4 * 32 + o], ehi = sEv[(c4 + 8) * 32 + o];
    float4 c0 = ((const float4*)ctr)[c4 * 3 + 0];
    float4 c1 = ((const float4*)ctr)[c4 * 3 + 1];
    float4 c2 = ((const float4*)ctr)[c4 * 3 + 2];
    float cv[12] = {c0.x, c0.y, c0.z, c0.w, c1.x, c1.y, c1.z, c1.w, c2.x, c2.y, c2.z, c2.w};
    #pragma unroll
    for (int v = 0; v < 12; ++v) {
      int cl = v / 3, d = v % 3;
      pcv[d] = fmaf(f4e(whi, cl) - f4e(wlo, cl), cv[v], pcv[d]);
      dcv[d] = fmaf(f4e(ehi, cl) - f4e(elo, cl), cv[v], dcv[d]);
    }
  }
  float acc[3] = {0, 0, 0};
  #pragma unroll 1
  for (int k = 0; k < 16; ++k) {
    int jn = kidx[k];
    const float* nb = yT + ((size_t)b * N_ + jn) * 96;
    float p[3] = {pcv[0], pcv[1], pcv[2]}, dd[3] = {dcv[0], dcv[1], dcv[2]};
    #pragma unroll
    for (int c4 = 0; c4 < 8; ++c4) {
      float4 w = sWv[c4 * 32 + o], e = sEv[c4 * 32 + o];
      float4 n0 = ((const float4*)nb)[c4 * 3 + 0];
      float4 n1 = ((const float4*)nb)[c4 * 3 + 1];
      float4 n2 = ((const float4*)nb)[c4 * 3 + 2];
      float nv[12] = {n0.x, n0.y, n0.z, n0.w, n1.x, n1.y, n1.z, n1.w, n2.x, n2.y, n2.z, n2.w};
      #pragma unroll
      for (int v = 0; v < 12; ++v) {
        int cl = v / 3, d = v % 3;
        p[d]  = fmaf(f4e(w, cl), nv[v], p[d]);
        dd[d] = fmaf(f4e(e, cl), nv[v], dd[d]);
      }
    }
    float dot = p[0] * dd[0] + p[1] * dd[1] + p[2] * dd[2];
    float dsq = dd[0] * dd[0] + dd[1] * dd[1] + dd[2] * dd[2] + 1e-6f;
    float r = dot / dsq;
    float attk = __shfl(att_mine, h * 16 + k, 32);
    #pragma unroll
    for (int d = 0; d < 3; ++d) {
      float pn = p[d] - r * dd[d];
      float vy = 0.2f * p[d] + 0.8f * (dot >= 0.f ? p[d] : pn);
      acc[d] = fmaf(attk, vy, acc[d]);
    }
  }

  #pragma unroll
  for (int d = 0; d < 3; ++d) sOut[q][o * 3 + d] = acc[d];
  __syncthreads();
  int nl = t & 7;
  int n_out = ((bno & 511) << 3) + nl;
  #pragma unroll
  for (int it = 0; it < 3; ++it) {
    int od = it * 32 + (t >> 3);
    size_t a = (size_t)b * 96 * N_ + (size_t)od * N_ + n_out;
    out[a] = x[a] + sOut[nl][od];
  }
}

extern "C" void kernel_launch(void* const* d_in, const int* in_sizes, int n_in,
                              void* d_out, int out_size, void* d_ws, size_t ws_size,
                              hipStream_t stream) {
  const float* x  = (const float*)d_in[0];
  const float* y  = (const float*)d_in[1];
  const float* Wq = (const float*)d_in[2];
  const float* Dq = (const float*)d_in[3];
  const float* Wk = (const float*)d_in[4];
  const float* Dk = (const float*)d_in[5];
  const float* Wv = (const float*)d_in[6];
  const float* Dv = (const float*)d_in[7];
  float* out = (float*)d_out;

  char* wsb = (char*)d_ws;
  float*  yT  = (float*)wsb;                                   // 12,582,912 B
  double* sqd = (double*)(wsb + 12582912);                     //    262,144 B
  float*  sq  = (float*)(wsb + 12845056);                      //    131,072 B
  int*    knn = (int*)(wsb + 12976128);                        //  2,097,152 B
  ushort* hBs = (ushort*)(wsb + 15073280);                     //  6,291,456 B
  ushort* lBs = (ushort*)(wsb + 21364736);                     //  6,291,456 B
  float*  Ek  = (float*)(wsb + 27656192);                      //      8,192 B
  float*  Ev  = Ek + 2048;
  float*  Eq  = Ev + 2048;

  kE_combine<<<dim3(1), dim3(256), 0, stream>>>(Wk, Dk, Wv, Dv, Wq, Dq, Ek, Ev, Eq);
  kA_transpose<<<dim3(512), dim3(256), 0, stream>>>(y, yT, sq, sqd, hBs, lBs);
  kB_knn<<<dim3(2048), dim3(256), 0, stream>>>(yT, hBs, lBs, sq, sqd, knn);
  kC_main<<<dim3(4096), dim3(256), 0, stream>>>(x, yT, knn, Wq, Eq, Wk, Ek, Wv, Ev, out);
}

// Round 9
// 1466.518 us; speedup vs baseline: 2.7397x; 2.7397x over previous
//
#include <hip/hip_runtime.h>
#include <math.h>
#include <float.h>
#include <limits.h>

#define B_ 8
#define C_ 32
#define N_ 4096
#define K_ 16
#define L_ 20   // per-lane candidate list length (margin 4 over 16)

typedef __attribute__((ext_vector_type(8))) short bf16x8;
typedef __attribute__((ext_vector_type(4))) float f32x4;
#define MFMA16(a, b, c) __builtin_amdgcn_mfma_f32_16x16x32_bf16(a, b, c, 0, 0, 0)

// ------------------------------------------------------------------
// ws layout (bytes):
//   yT  : [B][N][96] float    12,582,912
//   sqd : [B][N]     double      262,144
//   sq  : [B][N]     float       131,072
//   knn : [B][N][16] int       2,097,152
//   hBs : swizzled bf16 hi     6,291,456   (frag-major: [g16][sl][lane][8])
//   lBs : swizzled bf16 lo     6,291,456
//   Ek/Ev/Eq floats               20,480
// ------------------------------------------------------------------

__global__ __launch_bounds__(256) void kE_combine(
    const float* __restrict__ Wk, const float* __restrict__ Dk,
    const float* __restrict__ Wv, const float* __restrict__ Dv,
    const float* __restrict__ Wq, const float* __restrict__ Dq,
    float* __restrict__ Ek, float* __restrict__ Ev, float* __restrict__ Eq) {
  int t = threadIdx.x;
  for (int e = t; e < 2048; e += 256) {
    int o = e >> 6, c = e & 63;
    float a = 0.f, v = 0.f;
    for (int m = 0; m < 32; ++m) {
      a = fmaf(Dk[o * 32 + m], Wk[m * 64 + c], a);
      v = fmaf(Dv[o * 32 + m], Wv[m * 64 + c], v);
    }
    Ek[e] = a; Ev[e] = v;
  }
  for (int e = t; e < 1024; e += 256) {
    int o = e >> 5, c = e & 31;
    float a = 0.f;
    for (int m = 0; m < 32; ++m) a = fmaf(Dq[o * 32 + m], Wq[m * 32 + c], a);
    Eq[e] = a;
  }
}

// transpose y -> yT; sq fp32; sqd fp64; hBs/lBs = bf16 hi/lo split stored
// FRAGMENT-MAJOR: addr = ((g16*3 + sl)*64 + lane)*8 + e, lane=(fg<<4)|fm,
// point n = g16*16+fm, k-dim d = sl*32 + fg*8 + e.
__global__ __launch_bounds__(256) void kA_transpose(
    const float* __restrict__ y, float* __restrict__ yT,
    float* __restrict__ sq, double* __restrict__ sqd,
    ushort* __restrict__ hBs, ushort* __restrict__ lBs) {
  __shared__ float tile[96][65];
  int b = blockIdx.x >> 6;
  int n0 = (blockIdx.x & 63) * 64;
  int t = threadIdx.x;
  int g = t >> 6, ln = t & 63;
  #pragma unroll
  for (int r = 0; r < 24; ++r) {
    int d = g * 24 + r;
    tile[d][ln] = y[((size_t)b * 96 + d) * N_ + n0 + ln];
  }
  __syncthreads();
  if (t < 64) {
    float s = 0.f; double sd = 0.0;
    #pragma unroll
    for (int d = 0; d < 96; ++d) {
      float v = tile[d][t];
      s = fmaf(v, v, s);
      sd += (double)v * (double)v;
    }
    sq[b * N_ + n0 + t] = s;
    sqd[b * N_ + n0 + t] = sd;
  }
  for (int idx = t; idx < 64 * 96; idx += 256) {
    int nl = idx / 96, d = idx % 96;
    yT[((size_t)b * N_ + n0 + nl) * 96 + d] = tile[d][nl];
  }
  for (int idx = t; idx < 768; idx += 256) {
    int g16l = idx / 192;
    int rem = idx - g16l * 192;
    int sl = rem >> 6;
    int ln2 = rem & 63;
    int fg2 = ln2 >> 4, fm2 = ln2 & 15;
    int nl = g16l * 16 + fm2;
    uint hw[4], lw[4];
    #pragma unroll
    for (int e2 = 0; e2 < 4; ++e2) {
      float v0 = tile[sl * 32 + fg2 * 8 + 2 * e2][nl];
      float v1 = tile[sl * 32 + fg2 * 8 + 2 * e2 + 1][nl];
      uint x0 = __float_as_uint(v0), x1 = __float_as_uint(v1);
      uint h0 = x0 >> 16, h1 = x1 >> 16;
      float r0 = v0 - __uint_as_float(h0 << 16);
      float r1 = v1 - __uint_as_float(h1 << 16);
      uint l0 = __float_as_uint(r0) >> 16, l1 = __float_as_uint(r1) >> 16;
      hw[e2] = h0 | (h1 << 16);
      lw[e2] = l0 | (l1 << 16);
    }
    size_t off = (size_t)b * 393216 +
                 (((size_t)(n0 >> 4) + g16l) * 3 + sl) * 512 + (size_t)ln2 * 8;
    *(uint4*)(hBs + off) = make_uint4(hw[0], hw[1], hw[2], hw[3]);
    *(uint4*)(lBs + off) = make_uint4(lw[0], lw[1], lw[2], lw[3]);
  }
}

// Named-register top-20: 40 scalar variables, macro compare-exchange chain.
// Every access is compile-time static -> guaranteed register allocation
// (rule #20: runtime-indexed arrays demote to scratch, which was the
// invisible 20x cost in rounds 6-8: VGPR=84..108 proved the lists lived
// in scratch; L1/L2 absorbed the traffic so HBM counters looked clean).
#define DECL20 \
  float v0=-FLT_MAX,v1=-FLT_MAX,v2=-FLT_MAX,v3=-FLT_MAX,v4=-FLT_MAX, \
        v5=-FLT_MAX,v6=-FLT_MAX,v7=-FLT_MAX,v8=-FLT_MAX,v9=-FLT_MAX, \
        v10=-FLT_MAX,v11=-FLT_MAX,v12=-FLT_MAX,v13=-FLT_MAX,v14=-FLT_MAX, \
        v15=-FLT_MAX,v16=-FLT_MAX,v17=-FLT_MAX,v18=-FLT_MAX,v19=-FLT_MAX; \
  int y0=0,y1=0,y2=0,y3=0,y4=0,y5=0,y6=0,y7=0,y8=0,y9=0, \
      y10=0,y11=0,y12=0,y13=0,y14=0,y15=0,y16=0,y17=0,y18=0,y19=0;

#define CX(i) { bool cc = cv > v##i; \
  float tf = cc ? v##i : cv; int ti = cc ? y##i : ci; \
  v##i = cc ? cv : v##i; y##i = cc ? ci : y##i; cv = tf; ci = ti; }

#define INSERT20 { CX(0) CX(1) CX(2) CX(3) CX(4) CX(5) CX(6) CX(7) CX(8) CX(9) \
  CX(10) CX(11) CX(12) CX(13) CX(14) CX(15) CX(16) CX(17) CX(18) CX(19) }

// kNN: block = 16 queries x 4 j-chunk waves (2048 blocks, 8192 waves).
// Wave w scans j in [w*1024,(w+1)*1024): 16 tiles x {24 coalesced frag
// loads, 36 MFMA}; lane (fg,fm) keeps register top-20 of its 256 scores
// for query q=qg*16+fm. Epilogue: 16-way exact merge -> fp64 re-score
// of 20 -> exact sorted top-16.
__global__ __launch_bounds__(256) void kB_knn(
    const float* __restrict__ yT, const ushort* __restrict__ hBs,
    const ushort* __restrict__ lBs, const float* __restrict__ sq,
    const double* __restrict__ sqd, int* __restrict__ knn) {
  __shared__ float  lv[4][4][16][L_ + 1];   // [w][fg][fm][slot]
  __shared__ int    li[4][4][16][L_ + 1];
  __shared__ float  mv[16][L_];
  __shared__ int    mid[16][L_];
  __shared__ double rv[16][L_];

  const int t = threadIdx.x;
  const int lane = t & 63;
  const int w = t >> 6;
  const int fg = lane >> 4, fm = lane & 15;
  const int b = blockIdx.x & 7;             // XCD-friendly batch pinning
  const int qg = blockIdx.x >> 3;           // 0..255
  const int q = qg * 16 + fm;
  const size_t bN = (size_t)b * N_;
  const ushort* hb = hBs + bN * 96;
  const ushort* lb = lBs + bN * 96;
  const float* sqb = sq + bN;
  const float sqi = sqb[q];

  // resident query frags (B operand): h and l, 3 k-segments each
  const ushort* hqb = hb + (size_t)qg * 1536 + (size_t)lane * 8;
  const ushort* lqb = lb + (size_t)qg * 1536 + (size_t)lane * 8;
  const bf16x8 qh0 = *(const bf16x8*)(hqb);
  const bf16x8 qh1 = *(const bf16x8*)(hqb + 512);
  const bf16x8 qh2 = *(const bf16x8*)(hqb + 1024);
  const bf16x8 ql0 = *(const bf16x8*)(lqb);
  const bf16x8 ql1 = *(const bf16x8*)(lqb + 512);
  const bf16x8 ql2 = *(const bf16x8*)(lqb + 1024);

  DECL20

  const int jchunk = w * 1024;
  #pragma unroll 1
  for (int jt = 0; jt < 16; ++jt) {
    const int g16 = (jchunk >> 4) + jt * 4;
    const ushort* hpb = hb + (size_t)g16 * 1536 + (size_t)lane * 8;
    const ushort* lpb = lb + (size_t)g16 * 1536 + (size_t)lane * 8;
    #pragma unroll
    for (int jb = 0; jb < 4; ++jb) {
      const ushort* ph = hpb + jb * 1536;
      const ushort* pl = lpb + jb * 1536;
      const bf16x8 a0 = *(const bf16x8*)(ph);
      const bf16x8 a1 = *(const bf16x8*)(ph + 512);
      const bf16x8 a2 = *(const bf16x8*)(ph + 1024);
      const bf16x8 b0 = *(const bf16x8*)(pl);
      const bf16x8 b1 = *(const bf16x8*)(pl + 512);
      const bf16x8 b2 = *(const bf16x8*)(pl + 1024);
      f32x4 c = {0.f, 0.f, 0.f, 0.f};
      c = MFMA16(a0, qh0, c);   // h_j . h_q
      c = MFMA16(a1, qh1, c);
      c = MFMA16(a2, qh2, c);
      c = MFMA16(a0, ql0, c);   // h_j . l_q
      c = MFMA16(a1, ql1, c);
      c = MFMA16(a2, ql2, c);
      c = MFMA16(b0, qh0, c);   // l_j . h_q
      c = MFMA16(b1, qh1, c);
      c = MFMA16(b2, qh2, c);
      const int jbase = jchunk + jt * 64 + jb * 16 + fg * 4;
      const float4 s4 = *(const float4*)(sqb + jbase);
      #pragma unroll
      for (int r = 0; r < 4; ++r) {
        const float sj = r == 0 ? s4.x : r == 1 ? s4.y : r == 2 ? s4.z : s4.w;
        const float neg = 2.f * c[r] - sqi - sj;
        if (neg > v19) {                 // strict >: earlier index wins ties
          float cv = neg; int ci = jbase + r;
          INSERT20
        }
      }
    }
  }

  // ---- per-lane sorted lists + sentinel ----
  {
    float* lvp = &lv[w][fg][fm][0];
    int*   lip = &li[w][fg][fm][0];
    lvp[0]=v0; lvp[1]=v1; lvp[2]=v2; lvp[3]=v3; lvp[4]=v4;
    lvp[5]=v5; lvp[6]=v6; lvp[7]=v7; lvp[8]=v8; lvp[9]=v9;
    lvp[10]=v10; lvp[11]=v11; lvp[12]=v12; lvp[13]=v13; lvp[14]=v14;
    lvp[15]=v15; lvp[16]=v16; lvp[17]=v17; lvp[18]=v18; lvp[19]=v19;
    lvp[20]=-FLT_MAX;
    lip[0]=y0; lip[1]=y1; lip[2]=y2; lip[3]=y3; lip[4]=y4;
    lip[5]=y5; lip[6]=y6; lip[7]=y7; lip[8]=y8; lip[9]=y9;
    lip[10]=y10; lip[11]=y11; lip[12]=y12; lip[13]=y13; lip[14]=y14;
    lip[15]=y15; lip[16]=y16; lip[17]=y17; lip[18]=y18; lip[19]=y19;
    lip[20]=INT_MAX;
  }
  __syncthreads();

  // ---- 16-way exact merge (threads 0..15, one per query) ----
  if (t < 16) {
    int p[16];
    #pragma unroll
    for (int c2 = 0; c2 < 16; ++c2) p[c2] = 0;
    #pragma unroll 1
    for (int r = 0; r < L_; ++r) {
      float bv = -FLT_MAX; int bi2 = INT_MAX; int bc = 0;
      #pragma unroll
      for (int c2 = 0; c2 < 16; ++c2) {
        float v = lv[c2 >> 2][c2 & 3][t][p[c2]];
        int  id = li[c2 >> 2][c2 & 3][t][p[c2]];
        if (v > bv || (v == bv && id < bi2)) { bv = v; bi2 = id; bc = c2; }
      }
      mv[t][r] = bv; mid[t][r] = bi2;
      #pragma unroll
      for (int c2 = 0; c2 < 16; ++c2) p[c2] += (bc == c2);
    }
  }
  __syncthreads();

  // ---- fp64 exact re-score: 320 tasks (16 q x 20 cand) ----
  {
    const double* sqdb = sqd + bN;
    const float* yTb = yT + bN * 96;
    #pragma unroll 1
    for (int task = t; task < 16 * L_; task += 256) {
      const int fq = task / L_, slot = task - fq * L_;
      const int qq = qg * 16 + fq;
      const int j = mid[fq][slot];
      const float4* q4p = (const float4*)(yTb + (size_t)qq * 96);
      const float4* p4p = (const float4*)(yTb + (size_t)j * 96);
      double a0 = 0.0, a1 = 0.0, a2 = 0.0, a3 = 0.0;
      #pragma unroll 4
      for (int m = 0; m < 24; ++m) {
        float4 qm = q4p[m], pm = p4p[m];
        a0 += (double)qm.x * (double)pm.x;
        a1 += (double)qm.y * (double)pm.y;
        a2 += (double)qm.z * (double)pm.z;
        a3 += (double)qm.w * (double)pm.w;
      }
      rv[fq][slot] = 2.0 * ((a0 + a1) + (a2 + a3)) - sqdb[qq] - sqdb[j];
    }
  }
  __syncthreads();

  // ---- final exact sorted top-16 (threads 0..15) ----
  if (t < 16) {
    double bd[16]; int bix[16];
    #pragma unroll
    for (int i = 0; i < 16; ++i) { bd[i] = -DBL_MAX; bix[i] = INT_MAX; }
    #pragma unroll 1
    for (int r = 0; r < L_; ++r) {
      double v = rv[t][r]; int id = mid[t][r];
      if (v > bd[15] || (v == bd[15] && id < bix[15])) {
        #pragma unroll
        for (int i = 0; i < 16; ++i) {
          if (v > bd[i] || (v == bd[i] && id < bix[i])) {
            double tv = bd[i]; bd[i] = v; v = tv;
            int ti = bix[i]; bix[i] = id; id = ti;
          }
        }
      }
    }
    int* outp = knn + (bN + (size_t)(qg * 16 + t)) * 16;
    #pragma unroll
    for (int r = 0; r < 16; ++r) outp[r] = bix[r];
  }
}

__device__ __forceinline__ float f4e(const float4& v, int i) {
  return i == 0 ? v.x : i == 1 ? v.y : i == 2 ? v.z : v.w;
}

// Fused main (unchanged).
__global__ __launch_bounds__(256) void kC_main(
    const float* __restrict__ x, const float* __restrict__ yT,
    const int* __restrict__ knn,
    const float* __restrict__ Wq, const float* __restrict__ Eq,
    const float* __restrict__ Wk, const float* __restrict__ Ek,
    const float* __restrict__ Wv, const float* __restrict__ Ev,
    float* __restrict__ out) {
  __shared__ float4 sWq[8 * 32], sEq[8 * 32];
  __shared__ float4 sWk[16 * 32], sEk[16 * 32], sWv[16 * 32], sEv[16 * 32];
  __shared__ float sOut[8][97];

  int t = threadIdx.x;
  {
    int e = t;
    int c4 = e >> 5, o = e & 31;
    sWq[e] = ((const float4*)(Wq + o * 32))[c4];
    sEq[e] = ((const float4*)(Eq + o * 32))[c4];
  }
  for (int e = t; e < 512; e += 256) {
    int c4 = e >> 5, o = e & 31;
    sWk[e] = ((const float4*)(Wk + o * 64))[c4];
    sEk[e] = ((const float4*)(Ek + o * 64))[c4];
    sWv[e] = ((const float4*)(Wv + o * 64))[c4];
    sEv[e] = ((const float4*)(Ev + o * 64))[c4];
  }
  __syncthreads();

  int q = t >> 5, o = t & 31;
  int bno = blockIdx.x;
  int b = bno >> 9;
  int n = ((bno & 511) << 3) + q;
  int h = o >> 4, kk_mine = o & 15;

  const float* xb = x + (size_t)b * 96 * N_ + n;
  float pq[3] = {0, 0, 0}, dq[3] = {0, 0, 0};
  #pragma unroll
  for (int c4 = 0; c4 < 8; ++c4) {
    float4 wq = sWq[c4 * 32 + o], eq = sEq[c4 * 32 + o];
    #pragma unroll
    for (int i = 0; i < 4; ++i) {
      int c = c4 * 4 + i;
      float w = f4e(wq, i), e2 = f4e(eq, i);
      #pragma unroll
      for (int d = 0; d < 3; ++d) {
        float xv = xb[(size_t)(c * 3 + d) * N_];
        pq[d] = fmaf(w, xv, pq[d]);
        dq[d] = fmaf(e2, xv, dq[d]);
      }
    }
  }
  float Qx[3];
  {
    float dot = pq[0] * dq[0] + pq[1] * dq[1] + pq[2] * dq[2];
    float dsq = dq[0] * dq[0] + dq[1] * dq[1] + dq[2] * dq[2] + 1e-6f;
    float r = dot / dsq;
    float qv[3];
    #pragma unroll
    for (int d = 0; d < 3; ++d) {
      float pn = pq[d] - r * dq[d];
      qv[d] = 0.2f * pq[d] + 0.8f * (dot >= 0.f ? pq[d] : pn);
    }
    float nn = sqrtf(qv[0] * qv[0] + qv[1] * qv[1] + qv[2] * qv[2]);
    float nch2 = nn * nn;
    #pragma unroll
    for (int m = 1; m <= 16; m <<= 1) nch2 += __shfl_xor(nch2, m, 32);
    float s = (nn / fmaxf(sqrtf(nch2), 1e-12f)) / fmaxf(nn, 1e-12f);
    #pragma unroll
    for (int d = 0; d < 3; ++d) Qx[d] = qv[d] * s;
  }

  const float* ctr = yT + ((size_t)b * N_ + n) * 96;
  const int* kidx = knn + ((size_t)b * N_ + n) * 16;

  float pck[3] = {0, 0, 0}, dck[3] = {0, 0, 0};
  #pragma unroll
  for (int c4 = 0; c4 < 8; ++c4) {
    float4 wlo = sWk[c4 * 32 + o], whi = sWk[(c4 + 8) * 32 + o];
    float4 elo = sEk[c4 * 32 + o], ehi = sEk[(c4 + 8) * 32 + o];
    float4 c0 = ((const float4*)ctr)[c4 * 3 + 0];
    float4 c1 = ((const float4*)ctr)[c4 * 3 + 1];
    float4 c2 = ((const float4*)ctr)[c4 * 3 + 2];
    float cv[12] = {c0.x, c0.y, c0.z, c0.w, c1.x, c1.y, c1.z, c1.w, c2.x, c2.y, c2.z, c2.w};
    #pragma unroll
    for (int v = 0; v < 12; ++v) {
      int cl = v / 3, d = v % 3;
      pck[d] = fmaf(f4e(whi, cl) - f4e(wlo, cl), cv[v], pck[d]);
      dck[d] = fmaf(f4e(ehi, cl) - f4e(elo, cl), cv[v], dck[d]);
    }
  }

  float myscore = 0.f;
  #pragma unroll 1
  for (int k = 0; k < 16; ++k) {
    int jn = kidx[k];
    const float* nb = yT + ((size_t)b * N_ + jn) * 96;
    float p[3] = {pck[0], pck[1], pck[2]}, dd[3] = {dck[0], dck[1], dck[2]};
    #pragma unroll
    for (int c4 = 0; c4 < 8; ++c4) {
      float4 w = sWk[c4 * 32 + o], e = sEk[c4 * 32 + o];
      float4 n0 = ((const float4*)nb)[c4 * 3 + 0];
      float4 n1 = ((const float4*)nb)[c4 * 3 + 1];
      float4 n2 = ((const float4*)nb)[c4 * 3 + 2];
      float nv[12] = {n0.x, n0.y, n0.z, n0.w, n1.x, n1.y, n1.z, n1.w, n2.x, n2.y, n2.z, n2.w};
      #pragma unroll
      for (int v = 0; v < 12; ++v) {
        int cl = v / 3, d = v % 3;
        p[d]  = fmaf(f4e(w, cl), nv[v], p[d]);
        dd[d] = fmaf(f4e(e, cl), nv[v], dd[d]);
      }
    }
    float dot = p[0] * dd[0] + p[1] * dd[1] + p[2] * dd[2];
    float dsq = dd[0] * dd[0] + dd[1] * dd[1] + dd[2] * dd[2] + 1e-6f;
    float r = dot / dsq;
    float ky[3];
    #pragma unroll
    for (int d = 0; d < 3; ++d) {
      float pn = p[d] - r * dd[d];
      ky[d] = 0.2f * p[d] + 0.8f * (dot >= 0.f ? p[d] : pn);
    }
    float nn = sqrtf(ky[0] * ky[0] + ky[1] * ky[1] + ky[2] * ky[2]);
    float nch2 = nn * nn;
    #pragma unroll
    for (int m = 1; m <= 16; m <<= 1) nch2 += __shfl_xor(nch2, m, 32);
    float s = (1.f / fmaxf(sqrtf(nch2), 1e-12f)) * (nn / fmaxf(nn, 1e-12f));
    float qk = (ky[0] * Qx[0] + ky[1] * Qx[1] + ky[2] * Qx[2]) * s;
    #pragma unroll
    for (int m = 1; m <= 8; m <<= 1) qk += __shfl_xor(qk, m, 32);
    float score = qk * 0.14433756729740643f;   // 1/sqrt(48)
    if (kk_mine == k) myscore = score;
  }

  float att_mine;
  {
    float mx = myscore;
    #pragma unroll
    for (int m = 1; m <= 8; m <<= 1) mx = fmaxf(mx, __shfl_xor(mx, m, 32));
    float ex = expf(myscore - mx);
    float ss = ex;
    #pragma unroll
    for (int m = 1; m <= 8; m <<= 1) ss += __shfl_xor(ss, m, 32);
    att_mine = ex / ss;
  }

  float pcv[3] = {0, 0, 0}, dcv[3] = {0, 0, 0};
  #pragma unroll
  for (int c4 = 0; c4 < 8; ++c4) {
    float4 wlo = sWv[c4 * 32 + o], whi = sWv[(c4 + 8) * 32 + o];
    float4 elo = sEv[c4 * 32 + o], ehi = sEv[(c4 + 8) * 32 + o];
    float4 c0 = ((const float4*)ctr)[c4 * 3 + 0];
    float4 c1 = ((const float4*)ctr)[c4 * 3 + 1];
    float4 c2 = ((const float4*)ctr)[c4 * 3 + 2];
    float cv[12] = {c0.x, c0.y, c0.z, c0.w, c1.x, c1.y, c1.z, c1.w, c2.x, c2.y, c2.z, c2.w};
    #pragma unroll
    for (int v = 0; v < 12; ++v) {
      int cl = v / 3, d = v % 3;
      pcv[d] = fmaf(f4e(whi, cl) - f4e(wlo, cl), cv[v], pcv[d]);
      dcv[d] = fmaf(f4e(ehi, cl) - f4e(elo, cl), cv[v], dcv[d]);
    }
  }
  float acc[3] = {0, 0, 0};
  #pragma unroll 1
  for (int k = 0; k < 16; ++k) {
    int jn = kidx[k];
    const float* nb = yT + ((size_t)b * N_ + jn) * 96;
    float p[3] = {pcv[0], pcv[1], pcv[2]}, dd[3] = {dcv[0], dcv[1], dcv[2]};
    #pragma unroll
    for (int c4 = 0; c4 < 8; ++c4) {
      float4 w = sWv[c4 * 32 + o], e = sEv[c4 * 32 + o];
      float4 n0 = ((const float4*)nb)[c4 * 3 + 0];
      float4 n1 = ((const float4*)nb)[c4 * 3 + 1];
      float4 n2 = ((const float4*)nb)[c4 * 3 + 2];
      float nv[12] = {n0.x, n0.y, n0.z, n0.w, n1.x, n1.y, n1.z, n1.w, n2.x, n2.y, n2.z, n2.w};
      #pragma unroll
      for (int v = 0; v < 12; ++v) {
        int cl = v / 3, d = v % 3;
        p[d]  = fmaf(f4e(w, cl), nv[v], p[d]);
        dd[d] = fmaf(f4e(e, cl), nv[v], dd[d]);
      }
    }
    float dot = p[0] * dd[0] + p[1] * dd[1] + p[2] * dd[2];
    float dsq = dd[0] * dd[0] + dd[1] * dd[1] + dd[2] * dd[2] + 1e-6f;
    float r = dot / dsq;
    float attk = __shfl(att_mine, h * 16 + k, 32);
    #pragma unroll
    for (int d = 0; d < 3; ++d) {
      float pn = p[d] - r * dd[d];
      float vy = 0.2f * p[d] + 0.8f * (dot >= 0.f ? p[d] : pn);
      acc[d] = fmaf(attk, vy, acc[d]);
    }
  }

  #pragma unroll
  for (int d = 0; d < 3; ++d) sOut[q][o * 3 + d] = acc[d];
  __syncthreads();
  int nl = t & 7;
  int n_out = ((bno & 511) << 3) + nl;
  #pragma unroll
  for (int it = 0; it < 3; ++it) {
    int od = it * 32 + (t >> 3);
    size_t a = (size_t)b * 96 * N_ + (size_t)od * N_ + n_out;
    out[a] = x[a] + sOut[nl][od];
  }
}

extern "C" void kernel_launch(void* const* d_in, const int* in_sizes, int n_in,
                              void* d_out, int out_size, void* d_ws, size_t ws_size,
                              hipStream_t stream) {
  const float* x  = (const float*)d_in[0];
  const float* y  = (const float*)d_in[1];
  const float* Wq = (const float*)d_in[2];
  const float* Dq = (const float*)d_in[3];
  const float* Wk = (const float*)d_in[4];
  const float* Dk = (const float*)d_in[5];
  const float* Wv = (const float*)d_in[6];
  const float* Dv = (const float*)d_in[7];
  float* out = (float*)d_out;

  char* wsb = (char*)d_ws;
  float*  yT  = (float*)wsb;                                   // 12,582,912 B
  double* sqd = (double*)(wsb + 12582912);                     //    262,144 B
  float*  sq  = (float*)(wsb + 12845056);                      //    131,072 B
  int*    knn = (int*)(wsb + 12976128);                        //  2,097,152 B
  ushort* hBs = (ushort*)(wsb + 15073280);                     //  6,291,456 B
  ushort* lBs = (ushort*)(wsb + 21364736);                     //  6,291,456 B
  float*  Ek  = (float*)(wsb + 27656192);                      //      8,192 B
  float*  Ev  = Ek + 2048;
  float*  Eq  = Ev + 2048;

  kE_combine<<<dim3(1), dim3(256), 0, stream>>>(Wk, Dk, Wv, Dv, Wq, Dq, Ek, Ev, Eq);
  kA_transpose<<<dim3(512), dim3(256), 0, stream>>>(y, yT, sq, sqd, hBs, lBs);
  kB_knn<<<dim3(2048), dim3(256), 0, stream>>>(yT, hBs, lBs, sq, sqd, knn);
  kC_main<<<dim3(4096), dim3(256), 0, stream>>>(x, yT, knn, Wq, Eq, Wk, Ek, Wv, Ev, out);
}